// Round 1
// baseline (1272.826 us; speedup 1.0000x reference)
//
#include <hip/hip_runtime.h>
#include <hip/hip_bf16.h>

// Problem constants (fixed by the reference)
#define N_PTS 32768
#define K_CLU 8192
#define D_DIM 64
#define DECAYF 0.99f
#define OMDF   0.01f
#define EPSF   1e-5f

typedef _Float16 v8h __attribute__((ext_vector_type(8)));
typedef float    v4f __attribute__((ext_vector_type(4)));

// ---- workspace layout (bytes) ----
#define OFF_IDX    0                         // N int32            = 131072 B
#define OFF_COUNTS (131072)                  // K uint32           = 32768 B
#define OFF_DW     (131072 + 32768)          // K*D fp32           = 2097152 B
#define OFF_NSUM   (OFF_DW + 2097152)        // 1 fp32 (+pad)      = 16 B
#define OFF_EHI    (OFF_NSUM + 16)           // K*D f16            = 1048576 B
#define OFF_ELO    (OFF_EHI + 1048576)       // K*D f16            = 1048576 B
#define OFF_E2     (OFF_ELO + 1048576)       // K fp32             = 32768 B
#define WS_NEEDED  (OFF_E2 + 32768)

// ---------------------------------------------------------------------------
// prep: split embedding into f16 hi/lo, row norms e2[k], and sum(ema_cs)
// grid: 2048 conv blocks (wave-per-row) + 32 reduction blocks
// ---------------------------------------------------------------------------
__global__ __launch_bounds__(256) void vq_prep(
    const float* __restrict__ emb, const float* __restrict__ ema_cs,
    _Float16* __restrict__ ehi, _Float16* __restrict__ elo,
    float* __restrict__ e2, float* __restrict__ nsum)
{
    const int wave = threadIdx.x >> 6;
    const int lane = threadIdx.x & 63;
    if (blockIdx.x < 2048) {
        const int row = blockIdx.x * 4 + wave;           // 0..8191
        float v = emb[(size_t)row * D_DIM + lane];
        _Float16 h = (_Float16)v;
        _Float16 l = (_Float16)(v - (float)h);
        ehi[(size_t)row * D_DIM + lane] = h;
        elo[(size_t)row * D_DIM + lane] = l;
        float s = v * v;
        #pragma unroll
        for (int m = 1; m < 64; m <<= 1) s += __shfl_xor(s, m, 64);
        if (lane == 0) e2[row] = s;
    } else {
        const int t = (blockIdx.x - 2048) * 256 + threadIdx.x;  // 0..8191
        float v = ema_cs[t];
        #pragma unroll
        for (int m = 1; m < 64; m <<= 1) v += __shfl_xor(v, m, 64);
        if (lane == 0) atomicAdd(nsum, v);
    }
}

// ---------------------------------------------------------------------------
// main: 1024 blocks x 256 threads.
//   blockIdx%4==0  -> compute block (128 points): f16x3 MFMA distance argmin,
//                     counts/dw atomics, idx[] out.
//   else           -> zero block: stream zeros into encodings (1 GiB),
//                     nontemporal to spare L2 for the embedding stream.
// LDS: 128-cluster chunk of e_hi/e_lo (padded rows of 72 f16) + e2. ~37 KB ->
// exactly 4 blocks/CU, so one compute block + three zero blocks co-resident
// per CU: MFMA pipe and HBM-store pipe overlap.
// ---------------------------------------------------------------------------
__global__ __launch_bounds__(256) void vq_main(
    const float* __restrict__ x,
    const _Float16* __restrict__ ehi, const _Float16* __restrict__ elo,
    const float* __restrict__ e2,
    float* __restrict__ enc,
    int* __restrict__ idx_out,
    unsigned int* __restrict__ counts,
    float* __restrict__ dw)
{
    __shared__ _Float16 sEhi[128 * 72];
    __shared__ _Float16 sElo[128 * 72];
    __shared__ float    sE2[128];

    const unsigned bid = blockIdx.x;
    if ((bid & 3u) != 0u) {
        // ---- zero role: 768 blocks cover N*K floats of zeros ----
        const unsigned zid = bid - bid / 4u - 1u;            // 0..767
        const size_t nvec = (size_t)N_PTS * K_CLU / 4;       // float4 count
        v4f z = {0.f, 0.f, 0.f, 0.f};
        v4f* enc4 = (v4f*)enc;
        for (size_t v = (size_t)zid * 256 + threadIdx.x; v < nvec; v += 768u * 256u)
            __builtin_nontemporal_store(z, enc4 + v);
        return;
    }

    // ---- compute role ----
    const unsigned cb = bid >> 2;            // 0..255
    const int wave = threadIdx.x >> 6;
    const int lane = threadIdx.x & 63;
    const int quad = lane >> 4;
    const int l15  = lane & 15;
    const int ptbase = cb * 128 + wave * 32;

    // Load X fragments once (A layout: A[m=lane&15][k=quad*8+j]), f16 hi/lo split.
    v8h xh[2][2], xl[2][2];
    #pragma unroll
    for (int g = 0; g < 2; ++g) {
        const int pt = ptbase + g * 16 + l15;
        const float* xp = x + (size_t)pt * D_DIM + quad * 8;
        #pragma unroll
        for (int c = 0; c < 2; ++c) {
            float4 a = *(const float4*)(xp + c * 32);
            float4 b = *(const float4*)(xp + c * 32 + 4);
            float vv[8] = {a.x, a.y, a.z, a.w, b.x, b.y, b.z, b.w};
            v8h hh, ll;
            #pragma unroll
            for (int j = 0; j < 8; ++j) {
                _Float16 h = (_Float16)vv[j];
                hh[j] = h;
                ll[j] = (_Float16)(vv[j] - (float)h);
            }
            xh[g][c] = hh; xl[g][c] = ll;
        }
    }

    float best[8]; int bidx[8];
    #pragma unroll
    for (int i = 0; i < 8; ++i) { best[i] = 3.4e38f; bidx[i] = 0; }

    for (int chunk = 0; chunk < 64; ++chunk) {
        const int kbase = chunk * 128;
        __syncthreads();
        // stage 128 clusters of e_hi/e_lo into padded LDS rows (72 f16/row)
        {
            const uint4* gh = (const uint4*)(ehi + (size_t)kbase * D_DIM);
            const uint4* gl = (const uint4*)(elo + (size_t)kbase * D_DIM);
            #pragma unroll
            for (int it = 0; it < 4; ++it) {
                int u = threadIdx.x + 256 * it;   // 0..1023 units of 8 f16
                int row = u >> 3, uc = u & 7;
                *(uint4*)&sEhi[row * 72 + uc * 8] = gh[row * 8 + uc];
                *(uint4*)&sElo[row * 72 + uc * 8] = gl[row * 8 + uc];
            }
            if (threadIdx.x < 128) sE2[threadIdx.x] = e2[kbase + threadIdx.x];
        }
        __syncthreads();

        #pragma unroll
        for (int sub = 0; sub < 8; ++sub) {
            const int nl = sub * 16 + l15;
            v8h bh0 = *(const v8h*)&sEhi[nl * 72 + quad * 8];
            v8h bh1 = *(const v8h*)&sEhi[nl * 72 + 32 + quad * 8];
            v8h bl0 = *(const v8h*)&sElo[nl * 72 + quad * 8];
            v8h bl1 = *(const v8h*)&sElo[nl * 72 + 32 + quad * 8];
            const float e2v = sE2[nl];
            const int kidx = kbase + nl;
            #pragma unroll
            for (int g = 0; g < 2; ++g) {
                v4f acc = {0.f, 0.f, 0.f, 0.f};
                acc = __builtin_amdgcn_mfma_f32_16x16x32_f16(xh[g][0], bh0, acc, 0, 0, 0);
                acc = __builtin_amdgcn_mfma_f32_16x16x32_f16(xh[g][1], bh1, acc, 0, 0, 0);
                acc = __builtin_amdgcn_mfma_f32_16x16x32_f16(xl[g][0], bh0, acc, 0, 0, 0);
                acc = __builtin_amdgcn_mfma_f32_16x16x32_f16(xl[g][1], bh1, acc, 0, 0, 0);
                acc = __builtin_amdgcn_mfma_f32_16x16x32_f16(xh[g][0], bl0, acc, 0, 0, 0);
                acc = __builtin_amdgcn_mfma_f32_16x16x32_f16(xh[g][1], bl1, acc, 0, 0, 0);
                #pragma unroll
                for (int r = 0; r < 4; ++r) {
                    float dist = fmaf(acc[r], -2.0f, e2v);   // x2 omitted: row-constant
                    if (dist < best[g * 4 + r]) { best[g * 4 + r] = dist; bidx[g * 4 + r] = kidx; }
                }
            }
        }
    }

    // cross-lane argmin within each 16-lane group (cols), tie -> smaller index
    #pragma unroll
    for (int i = 0; i < 8; ++i) {
        #pragma unroll
        for (int m = 1; m < 16; m <<= 1) {
            float ov = __shfl_xor(best[i], m, 64);
            int   oi = __shfl_xor(bidx[i], m, 64);
            if (ov < best[i] || (ov == best[i] && oi < bidx[i])) { best[i] = ov; bidx[i] = oi; }
        }
    }

    // write indices + counts (lane 0 of each quad owns rows quad*4+r)
    if (l15 == 0) {
        #pragma unroll
        for (int g = 0; g < 2; ++g)
            #pragma unroll
            for (int r = 0; r < 4; ++r) {
                int p = ptbase + g * 16 + quad * 4 + r;
                idx_out[p] = bidx[g * 4 + r];
                atomicAdd(&counts[bidx[g * 4 + r]], 1u);
            }
    }

    // dw[k,:] += x[p,:] for each of this wave's 32 points (lane = d)
    #pragma unroll
    for (int j = 0; j < 32; ++j) {
        const int g = j >> 4, row = j & 15;
        const int src = (row >> 2) * 16;       // a lane in the owning quad
        const int r = row & 3;
        int k = __shfl(bidx[g * 4 + r], src, 64);
        float val = x[(size_t)(ptbase + j) * D_DIM + lane];
        atomicAdd(&dw[(size_t)k * D_DIM + lane], val);
    }
}

// ---------------------------------------------------------------------------
// finalize: EMA outputs over K*D (2048 blocks) + scatter ones (128 blocks)
// ---------------------------------------------------------------------------
__global__ __launch_bounds__(256) void vq_finalize(
    const float* __restrict__ emb, const float* __restrict__ ema_w,
    const float* __restrict__ ema_cs,
    const unsigned int* __restrict__ counts, const float* __restrict__ dw,
    const float* __restrict__ nsum, const int* __restrict__ idx,
    float* __restrict__ out)
{
    const size_t ENC = (size_t)N_PTS * K_CLU;
    float* out_codebook = out + ENC;
    float* out_cs       = out_codebook + (size_t)K_CLU * D_DIM;
    float* out_ema      = out_cs + K_CLU;
    float* out_emb      = out_ema + (size_t)K_CLU * D_DIM;

    if (blockIdx.x < 2048) {
        const int gid = blockIdx.x * 256 + threadIdx.x;   // 0..K*D-1
        const int k = gid >> 6, d = gid & 63;
        float dwv = dw[gid];
        float en  = DECAYF * ema_w[gid] + OMDF * dwv;
        float cnt = (float)counts[k];
        float cs_raw = DECAYF * ema_cs[k] + OMDF * cnt;
        // n = sum(cluster_size) = 0.99*sum(ema_cs) + 0.01*N  (sum(counts)==N exactly)
        float n  = DECAYF * nsum[0] + OMDF * (float)N_PTS;
        float cs = (cs_raw + EPSF) / (n + (float)K_CLU * EPSF) * n;
        out_codebook[gid] = emb[gid];
        out_ema[gid] = en;
        out_emb[gid] = en / cs;
        if (d == 0) out_cs[k] = cs;
    } else {
        const int i = (blockIdx.x - 2048) * 256 + threadIdx.x;  // 0..N-1
        out[(size_t)i * K_CLU + idx[i]] = 1.0f;
    }
}

extern "C" void kernel_launch(void* const* d_in, const int* in_sizes, int n_in,
                              void* d_out, int out_size, void* d_ws, size_t ws_size,
                              hipStream_t stream)
{
    const float* x      = (const float*)d_in[0];   // [N, D]
    const float* emb    = (const float*)d_in[1];   // [K, D]
    const float* ema_w  = (const float*)d_in[2];   // [K, D]
    const float* ema_cs = (const float*)d_in[3];   // [K]
    float* out = (float*)d_out;
    char* ws = (char*)d_ws;

    int*          idx    = (int*)(ws + OFF_IDX);
    unsigned int* counts = (unsigned int*)(ws + OFF_COUNTS);
    float*        dw     = (float*)(ws + OFF_DW);
    float*        nsum   = (float*)(ws + OFF_NSUM);
    _Float16*     ehi    = (_Float16*)(ws + OFF_EHI);
    _Float16*     elo    = (_Float16*)(ws + OFF_ELO);
    float*        e2     = (float*)(ws + OFF_E2);

    // zero counts+dw+nsum (contiguous region); graph-capture-safe async memset
    hipMemsetAsync(ws + OFF_COUNTS, 0, (OFF_NSUM + 16) - OFF_COUNTS, stream);

    vq_prep<<<2080, 256, 0, stream>>>(emb, ema_cs, ehi, elo, e2, nsum);
    vq_main<<<1024, 256, 0, stream>>>(x, ehi, elo, e2, out, idx, counts, dw);
    vq_finalize<<<2176, 256, 0, stream>>>(emb, ema_w, ema_cs, counts, dw, nsum, idx, out);
}

// Round 2
// 1085.938 us; speedup vs baseline: 1.1721x; 1.1721x over previous
//
#include <hip/hip_runtime.h>
#include <hip/hip_bf16.h>

// Problem constants (fixed by the reference)
#define N_PTS 32768
#define K_CLU 8192
#define D_DIM 64
#define DECAYF 0.99f
#define OMDF   0.01f
#define EPSF   1e-5f

typedef _Float16 v8h __attribute__((ext_vector_type(8)));
typedef float    v4f __attribute__((ext_vector_type(4)));

// ---- workspace layout (bytes) ----
#define OFF_IDX    0                         // N int32            = 131072 B
#define OFF_COUNTS (131072)                  // K uint32           = 32768 B
#define OFF_DW     (131072 + 32768)          // K*D fp32           = 2097152 B
#define OFF_NSUM   (OFF_DW + 2097152)        // 1 fp32 (+pad)      = 16 B
#define OFF_EHI    (OFF_NSUM + 16)           // K*D f16            = 1048576 B
#define OFF_ELO    (OFF_EHI + 1048576)       // K*D f16            = 1048576 B
#define OFF_E2     (OFF_ELO + 1048576)       // K fp32             = 32768 B

// ---------------------------------------------------------------------------
// prep: split embedding into f16 hi/lo, row norms e2[k], and sum(ema_cs)
// ---------------------------------------------------------------------------
__global__ __launch_bounds__(256) void vq_prep(
    const float* __restrict__ emb, const float* __restrict__ ema_cs,
    _Float16* __restrict__ ehi, _Float16* __restrict__ elo,
    float* __restrict__ e2, float* __restrict__ nsum)
{
    const int wave = threadIdx.x >> 6;
    const int lane = threadIdx.x & 63;
    if (blockIdx.x < 2048) {
        const int row = blockIdx.x * 4 + wave;           // 0..8191
        float v = emb[(size_t)row * D_DIM + lane];
        _Float16 h = (_Float16)v;
        _Float16 l = (_Float16)(v - (float)h);
        ehi[(size_t)row * D_DIM + lane] = h;
        elo[(size_t)row * D_DIM + lane] = l;
        float s = v * v;
        #pragma unroll
        for (int m = 1; m < 64; m <<= 1) s += __shfl_xor(s, m, 64);
        if (lane == 0) e2[row] = s;
    } else {
        const int t = (blockIdx.x - 2048) * 256 + threadIdx.x;  // 0..8191
        float v = ema_cs[t];
        #pragma unroll
        for (int m = 1; m < 64; m <<= 1) v += __shfl_xor(v, m, 64);
        if (lane == 0) atomicAdd(nsum, v);
    }
}

// ---------------------------------------------------------------------------
// fused main: 512 blocks x 256 threads, 2 blocks/CU, every block does BOTH
// roles (XCD-balanced by construction):
//   - 4 waves x 16 points: f16x3-split MFMA distance argmin over K=8192
//     (LDS-staged 128-cluster chunks of e_hi/e_lo, padded rows of 72 f16)
//   - each block zero-streams its contiguous 2 MiB slice of encodings,
//     8 nontemporal float4/thread interleaved into each of the 64 chunks,
//     so the HBM store pipe is fed continuously under MFMA/LDS compute.
// ---------------------------------------------------------------------------
__global__ __launch_bounds__(256) void vq_fused(
    const float* __restrict__ x,
    const _Float16* __restrict__ ehi, const _Float16* __restrict__ elo,
    const float* __restrict__ e2,
    float* __restrict__ enc,
    int* __restrict__ idx_out,
    unsigned int* __restrict__ counts,
    float* __restrict__ dw)
{
    __shared__ _Float16 sEhi[128 * 72];
    __shared__ _Float16 sElo[128 * 72];
    __shared__ float    sE2[128];

    const int bid  = blockIdx.x;             // 0..511
    const int tid  = threadIdx.x;
    const int wave = tid >> 6;
    const int lane = tid & 63;
    const int quad = lane >> 4;
    const int l15  = lane & 15;
    const int ptbase = bid * 64 + wave * 16;

    // Load this wave's 16-point X fragments once (A layout: A[m=lane&15][k=quad*8+j])
    v8h xh[2], xl[2];
    {
        const int pt = ptbase + l15;
        const float* xp = x + (size_t)pt * D_DIM + quad * 8;
        #pragma unroll
        for (int c = 0; c < 2; ++c) {
            float4 a = *(const float4*)(xp + c * 32);
            float4 b = *(const float4*)(xp + c * 32 + 4);
            float vv[8] = {a.x, a.y, a.z, a.w, b.x, b.y, b.z, b.w};
            v8h hh, ll;
            #pragma unroll
            for (int j = 0; j < 8; ++j) {
                _Float16 h = (_Float16)vv[j];
                hh[j] = h;
                ll[j] = (_Float16)(vv[j] - (float)h);
            }
            xh[c] = hh; xl[c] = ll;
        }
    }

    float best[4]; int bidx4[4];
    #pragma unroll
    for (int i = 0; i < 4; ++i) { best[i] = 3.4e38f; bidx4[i] = 0; }

    // zero-stream setup: block slice = 131072 float4 (2 MiB), 2048/chunk
    v4f* enc4 = (v4f*)enc;
    const size_t zbase = (size_t)bid * 131072 + tid;
    const v4f zz = {0.f, 0.f, 0.f, 0.f};

    for (int chunk = 0; chunk < 64; ++chunk) {
        const int kbase = chunk * 128;
        __syncthreads();
        // stage 128 clusters of e_hi/e_lo into padded LDS rows (72 f16/row)
        {
            const uint4* gh = (const uint4*)(ehi + (size_t)kbase * D_DIM);
            const uint4* gl = (const uint4*)(elo + (size_t)kbase * D_DIM);
            #pragma unroll
            for (int it = 0; it < 4; ++it) {
                int u = tid + 256 * it;   // 0..1023 units of 8 f16
                int row = u >> 3, uc = u & 7;
                *(uint4*)&sEhi[row * 72 + uc * 8] = gh[row * 8 + uc];
                *(uint4*)&sElo[row * 72 + uc * 8] = gl[row * 8 + uc];
            }
            if (tid < 128) sE2[tid] = e2[kbase + tid];
        }
        __syncthreads();

        // interleaved zero-stream: 8 float4/thread/chunk (drains during compute)
        {
            const size_t zo = zbase + (size_t)chunk * 2048;
            #pragma unroll
            for (int it = 0; it < 8; ++it)
                __builtin_nontemporal_store(zz, enc4 + zo + it * 256);
        }

        #pragma unroll
        for (int sub = 0; sub < 8; ++sub) {
            const int nl = sub * 16 + l15;
            v8h bh0 = *(const v8h*)&sEhi[nl * 72 + quad * 8];
            v8h bh1 = *(const v8h*)&sEhi[nl * 72 + 32 + quad * 8];
            v8h bl0 = *(const v8h*)&sElo[nl * 72 + quad * 8];
            v8h bl1 = *(const v8h*)&sElo[nl * 72 + 32 + quad * 8];
            const float e2v = sE2[nl];
            const int kidx = kbase + nl;
            v4f acc = {0.f, 0.f, 0.f, 0.f};
            acc = __builtin_amdgcn_mfma_f32_16x16x32_f16(xh[0], bh0, acc, 0, 0, 0);
            acc = __builtin_amdgcn_mfma_f32_16x16x32_f16(xh[1], bh1, acc, 0, 0, 0);
            acc = __builtin_amdgcn_mfma_f32_16x16x32_f16(xl[0], bh0, acc, 0, 0, 0);
            acc = __builtin_amdgcn_mfma_f32_16x16x32_f16(xl[1], bh1, acc, 0, 0, 0);
            acc = __builtin_amdgcn_mfma_f32_16x16x32_f16(xh[0], bl0, acc, 0, 0, 0);
            acc = __builtin_amdgcn_mfma_f32_16x16x32_f16(xh[1], bl1, acc, 0, 0, 0);
            #pragma unroll
            for (int r = 0; r < 4; ++r) {
                float dist = fmaf(acc[r], -2.0f, e2v);   // x^2 omitted: row-constant
                if (dist < best[r]) { best[r] = dist; bidx4[r] = kidx; }
            }
        }
    }

    // cross-lane argmin within each 16-lane group (cols), tie -> smaller index
    #pragma unroll
    for (int i = 0; i < 4; ++i) {
        #pragma unroll
        for (int m = 1; m < 16; m <<= 1) {
            float ov = __shfl_xor(best[i], m, 64);
            int   oi = __shfl_xor(bidx4[i], m, 64);
            if (ov < best[i] || (ov == best[i] && oi < bidx4[i])) { best[i] = ov; bidx4[i] = oi; }
        }
    }

    // write indices + counts (l15==0 lane of quad q owns C rows q*4+r)
    if (l15 == 0) {
        #pragma unroll
        for (int r = 0; r < 4; ++r) {
            int p = ptbase + quad * 4 + r;
            idx_out[p] = bidx4[r];
            atomicAdd(&counts[bidx4[r]], 1u);
        }
    }

    // dw[k,:] += x[p,:] for each of this wave's 16 points (lane = d)
    #pragma unroll
    for (int j = 0; j < 16; ++j) {
        const int src = (j >> 2) * 16;         // l15==0 lane of owning quad
        const int r = j & 3;
        int k = __shfl(bidx4[r], src, 64);
        float val = x[(size_t)(ptbase + j) * D_DIM + lane];
        atomicAdd(&dw[(size_t)k * D_DIM + lane], val);
    }
}

// ---------------------------------------------------------------------------
// finalize: EMA outputs over K*D (2048 blocks) + scatter ones (128 blocks)
// ---------------------------------------------------------------------------
__global__ __launch_bounds__(256) void vq_finalize(
    const float* __restrict__ emb, const float* __restrict__ ema_w,
    const float* __restrict__ ema_cs,
    const unsigned int* __restrict__ counts, const float* __restrict__ dw,
    const float* __restrict__ nsum, const int* __restrict__ idx,
    float* __restrict__ out)
{
    const size_t ENC = (size_t)N_PTS * K_CLU;
    float* out_codebook = out + ENC;
    float* out_cs       = out_codebook + (size_t)K_CLU * D_DIM;
    float* out_ema      = out_cs + K_CLU;
    float* out_emb      = out_ema + (size_t)K_CLU * D_DIM;

    if (blockIdx.x < 2048) {
        const int gid = blockIdx.x * 256 + threadIdx.x;   // 0..K*D-1
        const int k = gid >> 6, d = gid & 63;
        float dwv = dw[gid];
        float en  = DECAYF * ema_w[gid] + OMDF * dwv;
        float cnt = (float)counts[k];
        float cs_raw = DECAYF * ema_cs[k] + OMDF * cnt;
        // n = sum(cluster_size) = 0.99*sum(ema_cs) + 0.01*N  (sum(counts)==N exactly)
        float n  = DECAYF * nsum[0] + OMDF * (float)N_PTS;
        float cs = (cs_raw + EPSF) / (n + (float)K_CLU * EPSF) * n;
        out_codebook[gid] = emb[gid];
        out_ema[gid] = en;
        out_emb[gid] = en / cs;
        if (d == 0) out_cs[k] = cs;
    } else {
        const int i = (blockIdx.x - 2048) * 256 + threadIdx.x;  // 0..N-1
        out[(size_t)i * K_CLU + idx[i]] = 1.0f;
    }
}

extern "C" void kernel_launch(void* const* d_in, const int* in_sizes, int n_in,
                              void* d_out, int out_size, void* d_ws, size_t ws_size,
                              hipStream_t stream)
{
    const float* x      = (const float*)d_in[0];   // [N, D]
    const float* emb    = (const float*)d_in[1];   // [K, D]
    const float* ema_w  = (const float*)d_in[2];   // [K, D]
    const float* ema_cs = (const float*)d_in[3];   // [K]
    float* out = (float*)d_out;
    char* ws = (char*)d_ws;

    int*          idx    = (int*)(ws + OFF_IDX);
    unsigned int* counts = (unsigned int*)(ws + OFF_COUNTS);
    float*        dw     = (float*)(ws + OFF_DW);
    float*        nsum   = (float*)(ws + OFF_NSUM);
    _Float16*     ehi    = (_Float16*)(ws + OFF_EHI);
    _Float16*     elo    = (_Float16*)(ws + OFF_ELO);
    float*        e2     = (float*)(ws + OFF_E2);

    // zero counts+dw+nsum (contiguous region); graph-capture-safe async memset
    hipMemsetAsync(ws + OFF_COUNTS, 0, (OFF_NSUM + 16) - OFF_COUNTS, stream);

    vq_prep<<<2080, 256, 0, stream>>>(emb, ema_cs, ehi, elo, e2, nsum);
    vq_fused<<<512, 256, 0, stream>>>(x, ehi, elo, e2, out, idx, counts, dw);
    vq_finalize<<<2176, 256, 0, stream>>>(emb, ema_w, ema_cs, counts, dw, nsum, idx, out);
}

// Round 3
// 1075.782 us; speedup vs baseline: 1.1832x; 1.0094x over previous
//
#include <hip/hip_runtime.h>
#include <hip/hip_bf16.h>

// Problem constants (fixed by the reference)
#define N_PTS 32768
#define K_CLU 8192
#define D_DIM 64
#define DECAYF 0.99f
#define OMDF   0.01f
#define EPSF   1e-5f

typedef _Float16 v8h __attribute__((ext_vector_type(8)));
typedef float    v4f __attribute__((ext_vector_type(4)));

// ---- workspace layout (bytes) ----
#define OFF_COUNTS 0                         // K uint32           = 32768 B
#define OFF_DW     (32768)                   // K*D fp32           = 2097152 B
#define OFF_NSUM   (OFF_DW + 2097152)        // 1 fp32 (+pad)      = 16 B
#define OFF_EHI    (OFF_NSUM + 16)           // K*D f16            = 1048576 B
#define OFF_ELO    (OFF_EHI + 1048576)       // K*D f16            = 1048576 B
#define OFF_E2     (OFF_ELO + 1048576)       // K fp32             = 32768 B

// ---------------------------------------------------------------------------
// prep: split embedding into f16 hi/lo, row norms e2[k], and sum(ema_cs)
// ---------------------------------------------------------------------------
__global__ __launch_bounds__(256) void vq_prep(
    const float* __restrict__ emb, const float* __restrict__ ema_cs,
    _Float16* __restrict__ ehi, _Float16* __restrict__ elo,
    float* __restrict__ e2, float* __restrict__ nsum)
{
    const int wave = threadIdx.x >> 6;
    const int lane = threadIdx.x & 63;
    if (blockIdx.x < 2048) {
        const int row = blockIdx.x * 4 + wave;           // 0..8191
        float v = emb[(size_t)row * D_DIM + lane];
        _Float16 h = (_Float16)v;
        _Float16 l = (_Float16)(v - (float)h);
        ehi[(size_t)row * D_DIM + lane] = h;
        elo[(size_t)row * D_DIM + lane] = l;
        float s = v * v;
        #pragma unroll
        for (int m = 1; m < 64; m <<= 1) s += __shfl_xor(s, m, 64);
        if (lane == 0) e2[row] = s;
    } else {
        const int t = (blockIdx.x - 2048) * 256 + threadIdx.x;  // 0..8191
        float v = ema_cs[t];
        #pragma unroll
        for (int m = 1; m < 64; m <<= 1) v += __shfl_xor(v, m, 64);
        if (lane == 0) atomicAdd(nsum, v);
    }
}

// ---------------------------------------------------------------------------
// fused main: 512 blocks x 256 threads, 2 blocks/CU, XCD-balanced.
//   - 4 waves x 16 points: f16x3-split MFMA distance argmin over K=8192
//     (LDS-staged 128-cluster chunks of e_hi/e_lo, padded rows of 72 f16)
//   - each block zero-streams its OWN 64 rows of encodings (2 MiB slice =
//     rows [bid*64, bid*64+64)), one nontemporal float4/thread per sub-step
//     so the HBM store pipe is fed continuously under MFMA/LDS compute.
//   - after the K-loop (+barrier, which drains vmcnt), the argmin lanes
//     write the 1.0s directly into this block's rows — no separate scatter.
// ---------------------------------------------------------------------------
__global__ __launch_bounds__(256) void vq_fused(
    const float* __restrict__ x,
    const _Float16* __restrict__ ehi, const _Float16* __restrict__ elo,
    const float* __restrict__ e2,
    float* __restrict__ enc,
    unsigned int* __restrict__ counts,
    float* __restrict__ dw)
{
    __shared__ _Float16 sEhi[128 * 72];
    __shared__ _Float16 sElo[128 * 72];
    __shared__ float    sE2[128];

    const int bid  = blockIdx.x;             // 0..511
    const int tid  = threadIdx.x;
    const int lane = tid & 63;
    const int quad = lane >> 4;
    const int l15  = lane & 15;
    const int ptbase = bid * 64 + (tid >> 6) * 16;

    // Load this wave's 16-point X fragments once (A layout: A[m=lane&15][k=quad*8+j])
    v8h xh[2], xl[2];
    {
        const int pt = ptbase + l15;
        const float* xp = x + (size_t)pt * D_DIM + quad * 8;
        #pragma unroll
        for (int c = 0; c < 2; ++c) {
            float4 a = *(const float4*)(xp + c * 32);
            float4 b = *(const float4*)(xp + c * 32 + 4);
            float vv[8] = {a.x, a.y, a.z, a.w, b.x, b.y, b.z, b.w};
            v8h hh, ll;
            #pragma unroll
            for (int j = 0; j < 8; ++j) {
                _Float16 h = (_Float16)vv[j];
                hh[j] = h;
                ll[j] = (_Float16)(vv[j] - (float)h);
            }
            xh[c] = hh; xl[c] = ll;
        }
    }

    float best[4]; int bidx4[4];
    #pragma unroll
    for (int i = 0; i < 4; ++i) { best[i] = 3.4e38f; bidx4[i] = 0; }

    // zero-stream setup: block slice = 131072 float4 (2 MiB) = rows [bid*64,+64)
    v4f* enc4 = (v4f*)enc;
    const size_t zbase = (size_t)bid * 131072 + tid;
    const v4f zz = {0.f, 0.f, 0.f, 0.f};

    for (int chunk = 0; chunk < 64; ++chunk) {
        const int kbase = chunk * 128;
        __syncthreads();
        // stage 128 clusters of e_hi/e_lo into padded LDS rows (72 f16/row)
        {
            const uint4* gh = (const uint4*)(ehi + (size_t)kbase * D_DIM);
            const uint4* gl = (const uint4*)(elo + (size_t)kbase * D_DIM);
            #pragma unroll
            for (int it = 0; it < 4; ++it) {
                int u = tid + 256 * it;   // 0..1023 units of 8 f16
                int row = u >> 3, uc = u & 7;
                *(uint4*)&sEhi[row * 72 + uc * 8] = gh[row * 8 + uc];
                *(uint4*)&sElo[row * 72 + uc * 8] = gl[row * 8 + uc];
            }
            if (tid < 128) sE2[tid] = e2[kbase + tid];
        }
        __syncthreads();

        const size_t zo = zbase + (size_t)chunk * 2048;
        #pragma unroll
        for (int sub = 0; sub < 8; ++sub) {
            // paced zero-stream: 1 nontemporal float4/thread per sub-step
            __builtin_nontemporal_store(zz, enc4 + zo + sub * 256);

            const int nl = sub * 16 + l15;
            v8h bh0 = *(const v8h*)&sEhi[nl * 72 + quad * 8];
            v8h bh1 = *(const v8h*)&sEhi[nl * 72 + 32 + quad * 8];
            v8h bl0 = *(const v8h*)&sElo[nl * 72 + quad * 8];
            v8h bl1 = *(const v8h*)&sElo[nl * 72 + 32 + quad * 8];
            const float e2v = sE2[nl];
            const int kidx = kbase + nl;
            v4f acc = {0.f, 0.f, 0.f, 0.f};
            acc = __builtin_amdgcn_mfma_f32_16x16x32_f16(xh[0], bh0, acc, 0, 0, 0);
            acc = __builtin_amdgcn_mfma_f32_16x16x32_f16(xh[1], bh1, acc, 0, 0, 0);
            acc = __builtin_amdgcn_mfma_f32_16x16x32_f16(xl[0], bh0, acc, 0, 0, 0);
            acc = __builtin_amdgcn_mfma_f32_16x16x32_f16(xl[1], bh1, acc, 0, 0, 0);
            acc = __builtin_amdgcn_mfma_f32_16x16x32_f16(xh[0], bl0, acc, 0, 0, 0);
            acc = __builtin_amdgcn_mfma_f32_16x16x32_f16(xh[1], bl1, acc, 0, 0, 0);
            #pragma unroll
            for (int r = 0; r < 4; ++r) {
                float dist = fmaf(acc[r], -2.0f, e2v);   // x^2 omitted: row-constant
                if (dist < best[r]) { best[r] = dist; bidx4[r] = kidx; }
            }
        }
    }

    // cross-lane argmin within each 16-lane group (cols), tie -> smaller index
    #pragma unroll
    for (int i = 0; i < 4; ++i) {
        #pragma unroll
        for (int m = 1; m < 16; m <<= 1) {
            float ov = __shfl_xor(best[i], m, 64);
            int   oi = __shfl_xor(bidx4[i], m, 64);
            if (ov < best[i] || (ov == best[i] && oi < bidx4[i])) { best[i] = ov; bidx4[i] = oi; }
        }
    }

    // barrier: __syncthreads drains vmcnt, so all zero-stores of this block's
    // rows are in L2 before we overwrite the one-hot positions below.
    __syncthreads();

    // write ones + counts (l15==0 lane of quad q owns C rows q*4+r)
    if (l15 == 0) {
        #pragma unroll
        for (int r = 0; r < 4; ++r) {
            int p = ptbase + quad * 4 + r;
            enc[(size_t)p * K_CLU + bidx4[r]] = 1.0f;
            atomicAdd(&counts[bidx4[r]], 1u);
        }
    }

    // dw[k,:] += x[p,:] for each of this wave's 16 points (lane = d)
    #pragma unroll
    for (int j = 0; j < 16; ++j) {
        const int src = (j >> 2) * 16;         // l15==0 lane of owning quad
        const int r = j & 3;
        int k = __shfl(bidx4[r], src, 64);
        float val = x[(size_t)(ptbase + j) * D_DIM + lane];
        atomicAdd(&dw[(size_t)k * D_DIM + lane], val);
    }
}

// ---------------------------------------------------------------------------
// finalize: EMA outputs over K*D (2048 blocks); encodings fully written by fused
// ---------------------------------------------------------------------------
__global__ __launch_bounds__(256) void vq_finalize(
    const float* __restrict__ emb, const float* __restrict__ ema_w,
    const float* __restrict__ ema_cs,
    const unsigned int* __restrict__ counts, const float* __restrict__ dw,
    const float* __restrict__ nsum,
    float* __restrict__ out)
{
    const size_t ENC = (size_t)N_PTS * K_CLU;
    float* out_codebook = out + ENC;
    float* out_cs       = out_codebook + (size_t)K_CLU * D_DIM;
    float* out_ema      = out_cs + K_CLU;
    float* out_emb      = out_ema + (size_t)K_CLU * D_DIM;

    const int gid = blockIdx.x * 256 + threadIdx.x;   // 0..K*D-1
    const int k = gid >> 6, d = gid & 63;
    float dwv = dw[gid];
    float en  = DECAYF * ema_w[gid] + OMDF * dwv;
    float cnt = (float)counts[k];
    float cs_raw = DECAYF * ema_cs[k] + OMDF * cnt;
    // n = sum(cluster_size) = 0.99*sum(ema_cs) + 0.01*N  (sum(counts)==N exactly)
    float n  = DECAYF * nsum[0] + OMDF * (float)N_PTS;
    float cs = (cs_raw + EPSF) / (n + (float)K_CLU * EPSF) * n;
    out_codebook[gid] = emb[gid];
    out_ema[gid] = en;
    out_emb[gid] = en / cs;
    if (d == 0) out_cs[k] = cs;
}

extern "C" void kernel_launch(void* const* d_in, const int* in_sizes, int n_in,
                              void* d_out, int out_size, void* d_ws, size_t ws_size,
                              hipStream_t stream)
{
    const float* x      = (const float*)d_in[0];   // [N, D]
    const float* emb    = (const float*)d_in[1];   // [K, D]
    const float* ema_w  = (const float*)d_in[2];   // [K, D]
    const float* ema_cs = (const float*)d_in[3];   // [K]
    float* out = (float*)d_out;
    char* ws = (char*)d_ws;

    unsigned int* counts = (unsigned int*)(ws + OFF_COUNTS);
    float*        dw     = (float*)(ws + OFF_DW);
    float*        nsum   = (float*)(ws + OFF_NSUM);
    _Float16*     ehi    = (_Float16*)(ws + OFF_EHI);
    _Float16*     elo    = (_Float16*)(ws + OFF_ELO);
    float*        e2     = (float*)(ws + OFF_E2);

    // zero counts+dw+nsum (contiguous region); graph-capture-safe async memset
    hipMemsetAsync(ws + OFF_COUNTS, 0, (OFF_NSUM + 16) - OFF_COUNTS, stream);

    vq_prep<<<2080, 256, 0, stream>>>(emb, ema_cs, ehi, elo, e2, nsum);
    vq_fused<<<512, 256, 0, stream>>>(x, ehi, elo, e2, out, counts, dw);
    vq_finalize<<<2048, 256, 0, stream>>>(emb, ema_w, ema_cs, counts, dw, nsum, out);
}